// Round 1
// 11103.603 us; speedup vs baseline: 1.7653x; 1.7653x over previous
//
#include <hip/hip_runtime.h>
#include <stdint.h>

#define T_SEQ 1024
#define BATCH 32
#define HD    512
#define G3    1536   // 3*HD
#define RS    32     // blocks per direction in scan

typedef __attribute__((ext_vector_type(8))) short bf16x8;
typedef __attribute__((ext_vector_type(4))) float f32x4;
typedef __attribute__((ext_vector_type(4))) unsigned short us4;
typedef __attribute__((ext_vector_type(8))) unsigned short us8;
typedef unsigned long long u64;

__device__ __forceinline__ float bf2f(unsigned short u) {
    unsigned int v = ((unsigned int)u) << 16;
    float f; __builtin_memcpy(&f, &v, 4); return f;
}
__device__ __forceinline__ unsigned short f2bf(float f) {
    unsigned int u; __builtin_memcpy(&u, &f, 4);
    unsigned int r = ((u >> 16) & 1u) + 0x7FFFu;
    return (unsigned short)((u + r) >> 16);
}
__device__ __forceinline__ float fsig(float x)  { return 1.f / (1.f + __expf(-x)); }
__device__ __forceinline__ float ftanh(float x) { return 1.f - 2.f / (__expf(2.f * x) + 1.f); }

// load 8 consecutive elements as bf16 (converting from fp32 if needed)
template<typename T> __device__ __forceinline__ us8 load8(const T* p);
template<> __device__ __forceinline__ us8 load8<unsigned short>(const unsigned short* p) {
    return *(const us8*)p;
}
template<> __device__ __forceinline__ us8 load8<float>(const float* p) {
    f32x4 a = *(const f32x4*)p;
    f32x4 b = *(const f32x4*)(p + 4);
    us8 r;
    r[0]=f2bf(a[0]); r[1]=f2bf(a[1]); r[2]=f2bf(a[2]); r[3]=f2bf(a[3]);
    r[4]=f2bf(b[0]); r[5]=f2bf(b[1]); r[6]=f2bf(b[2]); r[7]=f2bf(b[3]);
    return r;
}

__device__ __forceinline__ u64 pack4bf(const float* v) {
    u64 u = 0;
    #pragma unroll
    for (int i = 0; i < 4; i++)
        u |= (u64)f2bf(v[i]) << (16 * i);
    return u;
}

// store 4 consecutive output values (bf16-packed u64 or f32x4)
template<typename DT> __device__ __forceinline__ void store4(DT* p, const float* v, u64 packed);
template<> __device__ __forceinline__ void store4<unsigned short>(unsigned short* p, const float* v, u64 packed) {
    (void)v;
    *(u64*)p = packed;
}
template<> __device__ __forceinline__ void store4<float>(float* p, const float* v, u64 packed) {
    (void)packed;
    f32x4 o; o[0]=v[0]; o[1]=v[1]; o[2]=v[2]; o[3]=v[3];
    *(f32x4*)p = o;
}

// ---------------------------------------------------------------------------
// Chunked gi GEMM (bf16 MFMA, fp32 acc, bf16 gi output) — UNCHANGED.
//   gi[dir][lt][g][b] = sum_k A[rowBase_dir + lt*32 + b][k] * W[g][k] + bih[g]
// ---------------------------------------------------------------------------
template<typename AT>
__global__ __launch_bounds__(256) void gi_gemm(
    const AT* __restrict__ A, int K, int rowBase0, int rowBase1,
    const float* __restrict__ W0, const float* __restrict__ W1,
    const float* __restrict__ b0, const float* __restrict__ b1,
    unsigned short* __restrict__ gi, int TC)
{
    const int dir = blockIdx.z;
    const int rowBase = dir ? rowBase1 : rowBase0;
    const float* W    = dir ? W1 : W0;
    const float* bias = dir ? b1 : b0;
    unsigned short* giD = gi + (size_t)dir * TC * G3 * BATCH;

    const int bm = blockIdx.y * 128;
    const int bn = blockIdx.x * 128;

    __shared__ __attribute__((aligned(16))) unsigned short As[128][40];
    __shared__ __attribute__((aligned(16))) unsigned short Bs[128][40];

    const int tid  = threadIdx.x;
    const int lane = tid & 63;
    const int wave = tid >> 6;
    const int wm = (wave & 1) * 64;
    const int wn = (wave >> 1) * 64;

    f32x4 acc[4][4];
    const f32x4 zz = {0.f, 0.f, 0.f, 0.f};
    #pragma unroll
    for (int i = 0; i < 4; i++)
        #pragma unroll
        for (int j = 0; j < 4; j++) acc[i][j] = zz;

    const int sc = (tid & 3) * 8;
    const int sr = tid >> 2;

    const int kIters = K >> 5;
    for (int kb = 0; kb < kIters; ++kb) {
        const int k0 = kb * 32;
        #pragma unroll
        for (int p = 0; p < 2; ++p) {
            const int row = sr + p * 64;
            *(us8*)(&As[row][sc]) = load8<AT>(A + (size_t)(rowBase + bm + row) * K + k0 + sc);
            *(us8*)(&Bs[row][sc]) = load8<float>(W + (size_t)(bn + row) * K + k0 + sc);
        }
        __syncthreads();
        bf16x8 af[4], bfr[4];
        #pragma unroll
        for (int i = 0; i < 4; i++) {
            af[i]  = *(const bf16x8*)(&As[wm + i * 16 + (lane & 15)][(lane >> 4) * 8]);
            bfr[i] = *(const bf16x8*)(&Bs[wn + i * 16 + (lane & 15)][(lane >> 4) * 8]);
        }
        #pragma unroll
        for (int i = 0; i < 4; i++)
            #pragma unroll
            for (int j = 0; j < 4; j++)
                acc[i][j] = __builtin_amdgcn_mfma_f32_16x16x32_bf16(af[i], bfr[j], acc[i][j], 0, 0, 0);
        __syncthreads();
    }

    #pragma unroll
    for (int j = 0; j < 4; j++) {
        const int g = bn + wn + j * 16 + (lane & 15);
        const float bv = bias[g];
        #pragma unroll
        for (int i = 0; i < 4; i++) {
            const int m  = bm + wm + i * 16 + ((lane >> 4) * 4);
            const int lt = m >> 5;
            const int bb = m & 31;
            us4 o;
            #pragma unroll
            for (int q = 0; q < 4; q++) o[q] = f2bf(acc[i][j][q] + bv);
            *(us4*)(giD + ((size_t)lt * G3 + g) * BATCH + bb) = o;
        }
    }
}

// ---------------------------------------------------------------------------
// Persistent GRU scan, fence-free coherent h-exchange.
//   - Swapped MFMA operands: out[g][b] = Whh · h^T. Each thread owns
//     (batch bown, 4 consecutive hidden cols j0..j0+3) -> h publish is ONE
//     8-byte agent-scope atomic store (write-through to L3, no L2 flush).
//   - h reads: 16 batched global_load_dwordx4 sc0 sc1 (bypass L1/L2, read
//     from coherence point), single s_waitcnt vmcnt(0) + sched_barrier(0).
//   - NO agent fences: L2 stays warm for gi stream; no WB/INV sweeps on the
//     per-step critical path.
// ---------------------------------------------------------------------------
template<typename DT>
__global__ __launch_bounds__(128, 1) void gru_scan(
    const unsigned short* __restrict__ gi,     // [2][TC][G3][B] bf16
    const float* Wf, const float* Wb, const float* bhf, const float* bhb,
    const float* __restrict__ h0l,             // layer base: [2][32][512] fp32
    DT* __restrict__ dst,                      // [T][B][1024]
    float* __restrict__ finals,                // layer base: [2][32][512] fp32
    unsigned short* __restrict__ hbuf,         // [2 dir][2 par][32][512] bf16
    float* __restrict__ hf32,                  // [2 dir][32][512] fp32
    unsigned int* __restrict__ cnt,            // chunk base: [2 dir] x 64
    int c, int TC, int nc)
{
    const int blk   = blockIdx.x;
    const int dir   = blk >> 5;
    const int sl    = blk & 31;
    const int jbase = sl * 16;

    const float* W   = dir ? Wb  : Wf;
    const float* bhh = dir ? bhb : bhf;
    const unsigned short* giD = gi + (size_t)dir * TC * G3 * BATCH;
    unsigned short* hb = hbuf + (size_t)dir * 2 * BATCH * HD;
    float* hfd = hf32 + (size_t)dir * BATCH * HD;
    unsigned int* cc = cnt + (size_t)dir * 64;

    const int tid  = threadIdx.x;
    const int lane = tid & 63;
    const int wave = tid >> 6;      // batch halves 0-15 / 16-31
    const int l15  = lane & 15;
    const int quad = lane >> 4;
    const int bown = wave * 16 + l15;        // batch this thread owns
    const int j0   = jbase + quad * 4;       // 4 consecutive hidden cols owned

    __shared__ __attribute__((aligned(16))) unsigned short wlds[48 * 520];

    // Stage Whh slice (48 rows x 512, bf16) into LDS — unchanged layout.
    for (int idx = tid; idx < 48 * 64; idx += 128) {
        const int r   = idx >> 6;
        const int ch  = (idx & 63) * 8;
        const int q   = r >> 4;
        const int rr  = r & 15;
        *(us8*)(&wlds[r * 520 + ch]) = load8<float>(W + (size_t)(q * HD + jbase + rr) * HD + ch);
    }

    float hown[4];
    if (c == 0) {
        const float* h0d = h0l + (size_t)dir * BATCH * HD;
        f32x4 t4 = *(const f32x4*)(h0d + (size_t)bown * HD + j0);
        #pragma unroll
        for (int i = 0; i < 4; i++) hown[i] = t4[i];
    } else {
        f32x4 t4 = *(const f32x4*)(hfd + (size_t)bown * HD + j0);
        #pragma unroll
        for (int i = 0; i < 4; i++) hown[i] = t4[i];
    }

    const f32x4 bh_r = *(const f32x4*)(bhh + 0 * HD + j0);
    const f32x4 bh_z = *(const f32x4*)(bhh + 1 * HD + j0);
    const f32x4 bh_n = *(const f32x4*)(bhh + 2 * HD + j0);

    // Publish initial h into buffer 0 (coherent 8B store; drained by the
    // compiler's vmcnt(0) before s_barrier, then counted).
    __hip_atomic_store((u64*)(hb + (size_t)bown * HD + j0), pack4bf(hown),
                       __ATOMIC_RELAXED, __HIP_MEMORY_SCOPE_AGENT);
    __syncthreads();
    if (tid == 0)
        __hip_atomic_fetch_add(cc, 1u, __ATOMIC_RELAXED, __HIP_MEMORY_SCOPE_AGENT);

    for (int ls = 0; ls < TC; ++ls) {
        const int s  = c * TC + ls;
        const int t  = dir ? (T_SEQ - 1 - s) : s;
        const int lt = dir ? (TC - 1 - ls) : ls;
        const size_t gb = (size_t)lt * G3 * BATCH;

        // Prefetch gi for (bown, j0..j0+3) x 3 gates before the wait
        // (normal cached loads; L2 stays warm — no more invalidate storms).
        unsigned short gv[3][4];
        #pragma unroll
        for (int g = 0; g < 3; ++g)
            #pragma unroll
            for (int i = 0; i < 4; ++i)
                gv[g][i] = giD[gb + (size_t)(g * HD + j0 + i) * BATCH + bown];

        if (tid == 0) {
            const unsigned int target = (unsigned int)RS * (unsigned int)(ls + 1);
            while (__hip_atomic_load(cc, __ATOMIC_RELAXED, __HIP_MEMORY_SCOPE_AGENT) < target)
                __builtin_amdgcn_s_sleep(1);
        }
        __syncthreads();

        // Batched coherent h read: full 512-wide row of own batch, 16x16B.
        const unsigned short* hread = hb + (size_t)(ls & 1) * BATCH * HD;
        const unsigned short* hbase = hread + (size_t)bown * HD + quad * 8;
        bf16x8 hfr[16];
#define HLD(I, OFF) asm volatile("global_load_dwordx4 %0, %1, off offset:" #OFF " sc0 sc1" \
                                 : "=v"(hfr[I]) : "v"(hbase) : "memory")
        HLD(0, 0);    HLD(1, 64);   HLD(2, 128);  HLD(3, 192);
        HLD(4, 256);  HLD(5, 320);  HLD(6, 384);  HLD(7, 448);
        HLD(8, 512);  HLD(9, 576);  HLD(10, 640); HLD(11, 704);
        HLD(12, 768); HLD(13, 832); HLD(14, 896); HLD(15, 960);
#undef HLD
        asm volatile("s_waitcnt vmcnt(0)" ::: "memory");
        __builtin_amdgcn_sched_barrier(0);   // rule #18: keep MFMAs below the wait

        f32x4 ar = {0.f,0.f,0.f,0.f}, az = {0.f,0.f,0.f,0.f}, an = {0.f,0.f,0.f,0.f};
        #pragma unroll
        for (int kk = 0; kk < 16; ++kk) {
            const bf16x8 wr  = *(const bf16x8*)(&wlds[( 0 + l15) * 520 + kk * 32 + quad * 8]);
            const bf16x8 wz  = *(const bf16x8*)(&wlds[(16 + l15) * 520 + kk * 32 + quad * 8]);
            const bf16x8 wn_ = *(const bf16x8*)(&wlds[(32 + l15) * 520 + kk * 32 + quad * 8]);
            // C[row=g][col=b]: first operand supplies rows (W), second cols (h).
            ar = __builtin_amdgcn_mfma_f32_16x16x32_bf16(wr,  hfr[kk], ar, 0, 0, 0);
            az = __builtin_amdgcn_mfma_f32_16x16x32_bf16(wz,  hfr[kk], az, 0, 0, 0);
            an = __builtin_amdgcn_mfma_f32_16x16x32_bf16(wn_, hfr[kk], an, 0, 0, 0);
        }

        float hnv[4];
        #pragma unroll
        for (int i = 0; i < 4; i++) {
            const float r = fsig(bf2f(gv[0][i]) + ar[i] + bh_r[i]);
            const float z = fsig(bf2f(gv[1][i]) + az[i] + bh_z[i]);
            const float n = ftanh(bf2f(gv[2][i]) + r * (an[i] + bh_n[i]));
            hnv[i] = (1.f - z) * n + z * hown[i];
            hown[i] = hnv[i];
        }

        unsigned short* hwrite = hb + (size_t)((ls + 1) & 1) * BATCH * HD;
        const u64 hp = pack4bf(hnv);
        __hip_atomic_store((u64*)(hwrite + (size_t)bown * HD + j0), hp,
                           __ATOMIC_RELAXED, __HIP_MEMORY_SCOPE_AGENT);
        store4<DT>(dst + ((size_t)t * BATCH + bown) * 1024 + dir * HD + j0, hnv, hp);

        __syncthreads();   // drains the coherent store (vmcnt(0) before barrier)
        if (tid == 0)
            __hip_atomic_fetch_add(cc, 1u, __ATOMIC_RELAXED, __HIP_MEMORY_SCOPE_AGENT);
    }

    {
        f32x4 o; o[0]=hown[0]; o[1]=hown[1]; o[2]=hown[2]; o[3]=hown[3];
        *(f32x4*)(hfd + (size_t)bown * HD + j0) = o;
        if (c == nc - 1) {
            float* find = finals + (size_t)dir * BATCH * HD;
            *(f32x4*)(find + (size_t)bown * HD + j0) = o;
        }
    }
}

// ---------------------------------------------------------------------------
extern "C" void kernel_launch(void* const* d_in, const int* in_sizes, int n_in,
                              void* d_out, int out_size, void* d_ws, size_t ws_size,
                              hipStream_t stream)
{
    (void)in_sizes; (void)n_in; (void)out_size;

    const float* x  = (const float*)d_in[0];
    const float* h0 = (const float*)d_in[1];
    auto P = [&](int l, int k) { return (const float*)d_in[2 + l * 8 + k]; };
    // k: 0 wih, 1 whh, 2 bih, 3 bhh, 4 wihr, 5 whhr, 6 bihr, 7 bhhr

    const size_t OUTE = (size_t)T_SEQ * BATCH * 1024;   // sequence elems

    // pick largest chunk TC whose footprint fits ws_size (floor TC=8)
    int TC = 256;
    for (;;) {
        const size_t cntB = (size_t)3 * (T_SEQ / TC) * 128 * 4;
        const size_t giB  = (size_t)2 * TC * G3 * BATCH * 2;
        const size_t need = 262144 + cntB + giB + OUTE * 2;  // hbuf+hf32, cnt, gi, act1(bf16)
        if (need <= ws_size || TC == 8) break;
        TC >>= 1;
    }
    const int NC = T_SEQ / TC;
    const size_t cntB = (size_t)3 * NC * 128 * 4;

    unsigned char* w = (unsigned char*)d_ws;
    unsigned short* hbuf = (unsigned short*)w;                     // 131072 B
    float*          hf32 = (float*)(w + 131072);                   // 131072 B
    unsigned int*   cnts = (unsigned int*)(w + 262144);            // cntB
    unsigned short* gi   = (unsigned short*)(w + 262144 + cntB);
    unsigned short* act1 = gi + (size_t)2 * TC * G3 * BATCH;       // OUTE bf16

    float* out0f = (float*)d_out;                 // fp32 output 0 [T][B][1024]
    float* finf  = out0f + OUTE;                  // fp32 output 1 [6][32][512]
    unsigned short* act0 = (unsigned short*)d_out; // l0 bf16 scratch (first half
                                                   // of out0 bytes; consumed by
                                                   // l1 GEMM before l2 scan
                                                   // rewrites out0 as fp32)

    hipMemsetAsync(cnts, 0, cntB, stream);

    for (int l = 0; l < 3; ++l) {
        const int K = (l == 0) ? 256 : 1024;
        float* finl = finf + (size_t)l * 2 * BATCH * HD;
        const float* h0l = h0 + (size_t)l * 2 * BATCH * HD;

        for (int c = 0; c < NC; ++c) {
            const int rowBase0 = c * TC * 32;
            const int rowBase1 = (T_SEQ - (c + 1) * TC) * 32;
            const dim3 ggrid(12, (TC * 32) / 128, 2);

            if (l == 0) {
                gi_gemm<float><<<ggrid, 256, 0, stream>>>(
                    x, K, rowBase0, rowBase1,
                    P(l,0), P(l,4), P(l,2), P(l,6), gi, TC);
            } else {
                const unsigned short* actIn = (l == 1) ? act0 : act1;
                gi_gemm<unsigned short><<<ggrid, 256, 0, stream>>>(
                    actIn, K, rowBase0, rowBase1,
                    P(l,0), P(l,4), P(l,2), P(l,6), gi, TC);
            }

            unsigned int* cntp = cnts + (size_t)(l * NC + c) * 128;
            if (l == 0) {
                gru_scan<unsigned short><<<dim3(64), 128, 0, stream>>>(
                    gi, P(l,1), P(l,5), P(l,3), P(l,7), h0l,
                    act0, finl, hbuf, hf32, cntp, c, TC, NC);
            } else if (l == 1) {
                gru_scan<unsigned short><<<dim3(64), 128, 0, stream>>>(
                    gi, P(l,1), P(l,5), P(l,3), P(l,7), h0l,
                    act1, finl, hbuf, hf32, cntp, c, TC, NC);
            } else {
                gru_scan<float><<<dim3(64), 128, 0, stream>>>(
                    gi, P(l,1), P(l,5), P(l,3), P(l,7), h0l,
                    out0f, finl, hbuf, hf32, cntp, c, TC, NC);
            }
        }
    }
}